// Round 12
// baseline (2248.388 us; speedup 1.0000x reference)
//
#include <hip/hip_runtime.h>

// DigitCaps routing, fused. Logits are linear in v: b_k = u_hat . Vsum_k,
// so no [B,R,C] state is materialized; u_hat is recomputed per phase.
//
// Round-8 post-mortem: three different kernels all pinned at ~500us/pass with
// VALU<6%, HBM<1%, 0 bank conflicts, spill fixed -- and FIRST==!FIRST time.
// Surviving suspects: 2 waves/SIMD (no latency hiding) + I$ thrash (~25KB
// fully-unrolled body). Round-9: 1024-thr blocks (4 waves/SIMD), ROLLED
// c-loops with online softmax (hot code ~5KB, VGPR ~70), one r per wave.
// Rounds 9-11 never ran (GPU acquisition timeouts); resubmitting unchanged.

#define NBATCH 512
#define NR     1152
#define NCLS   10
#define NOUT   16
#define CO     160         // NCLS*NOUT

__device__ __forceinline__ unsigned short f2bf_rne(float x) {
    unsigned u = __float_as_uint(x);
    return (unsigned short)((u + 0x7fffu + ((u >> 16) & 1u)) >> 16);
}
__device__ __forceinline__ unsigned pack2(float lo, float hi) {
    return ((unsigned)f2bf_rne(hi) << 16) | f2bf_rne(lo);
}
__device__ __forceinline__ float bflo(unsigned q) { return __uint_as_float(q << 16); }
__device__ __forceinline__ float bfhi(unsigned q) { return __uint_as_float(q & 0xffff0000u); }

__device__ __forceinline__ float4 fma4(float s, float4 w, float4 a) {
    a.x = __builtin_fmaf(s, w.x, a.x);
    a.y = __builtin_fmaf(s, w.y, a.y);
    a.z = __builtin_fmaf(s, w.z, a.z);
    a.w = __builtin_fmaf(s, w.w, a.w);
    return a;
}
__device__ __forceinline__ float dot8(float4 a, float4 b, uint4 q, float acc) {
    acc = __builtin_fmaf(a.x, bflo(q.x), acc);
    acc = __builtin_fmaf(a.y, bfhi(q.x), acc);
    acc = __builtin_fmaf(a.z, bflo(q.y), acc);
    acc = __builtin_fmaf(a.w, bfhi(q.y), acc);
    acc = __builtin_fmaf(b.x, bflo(q.z), acc);
    acc = __builtin_fmaf(b.y, bfhi(q.z), acc);
    acc = __builtin_fmaf(b.z, bflo(q.w), acc);
    acc = __builtin_fmaf(b.w, bfhi(q.w), acc);
    return acc;
}

template<int RCH, bool FIRST>
__global__ __launch_bounds__(1024, 4)
void caps_pass(const float* __restrict__ U, const float* __restrict__ W,
               const float* __restrict__ Vs, float* __restrict__ Pg)
{
    __shared__ float wt[RCH * 1280];             // RCH=16: 80 KB (f32 W chunk)
    __shared__ float s_part[64][161];            // 41.2 KB, odd stride: 2-way = free
    __shared__ uint4 vs_sm[2 * NCLS * 64];       // 20 KB bf16 Vsum, lane-major (dropped when FIRST)

    const int tid  = threadIdx.x;
    const int lane = tid & 63;
    const int b0   = ((int)blockIdx.y) << 6;     // 64 batches/block, lane = batch
    const int rbase = (int)blockIdx.x * RCH;

    // stage W chunk (coalesced float4)
    {
        const float4* Wg4 = reinterpret_cast<const float4*>(W + (size_t)rbase * 1280);
        float4* wt4 = reinterpret_cast<float4*>(wt);
        for (int k = tid; k < RCH * 320; k += 1024)
            wt4[k] = Wg4[k];
    }
    // stage Vsum as packed bf16, lane-major [k=0..19][lane]
    if (!FIRST) {
        for (int f = tid; f < 2 * NCLS * 64; f += 1024) {
            const int k = f >> 6, l = f & 63;
            const float* vrow = Vs + (size_t)(b0 + l) * CO + k * 8;
            float4 a = *reinterpret_cast<const float4*>(vrow);
            float4 b = *reinterpret_cast<const float4*>(vrow + 4);
            uint4 q;
            q.x = pack2(a.x, a.y);
            q.y = pack2(a.z, a.w);
            q.z = pack2(b.x, b.y);
            q.w = pack2(b.z, b.w);
            vs_sm[f] = q;
        }
    }
    for (int idx = tid; idx < 64 * 161; idx += 1024)
        (&s_part[0][0])[idx] = 0.0f;
    __syncthreads();

    const int wv = __builtin_amdgcn_readfirstlane(tid >> 6);   // 0..15, wave = r

    for (int rl = wv; rl < RCH; rl += 16) {
        const float4* up = reinterpret_cast<const float4*>(
            U + (size_t)(b0 + lane) * (NR * 8) + (size_t)(rbase + rl) * 8);
        const float4 u0 = up[0], u1 = up[1];
        const float uu[8] = {u0.x, u0.y, u0.z, u0.w, u1.x, u1.y, u1.z, u1.w};
        const float4* wp = reinterpret_cast<const float4*>(wt + rl * 1280);

        float m = -1e30f, inv = 0.0f;

        if (!FIRST) {
            // phase 1: online softmax over classes (rolled loop, small code)
            float den = 0.0f;
            #pragma unroll 1
            for (int c = 0; c < NCLS; ++c) {
                float4 A0 = {0,0,0,0}, A1 = {0,0,0,0}, A2 = {0,0,0,0}, A3 = {0,0,0,0};
                #pragma unroll
                for (int i = 0; i < 8; ++i) {
                    const float ui = uu[i];
                    A0 = fma4(ui, wp[c*32 + i*4 + 0], A0);
                    A1 = fma4(ui, wp[c*32 + i*4 + 1], A1);
                    A2 = fma4(ui, wp[c*32 + i*4 + 2], A2);
                    A3 = fma4(ui, wp[c*32 + i*4 + 3], A3);
                }
                const uint4 qa = vs_sm[(2*c)     * 64 + lane];
                const uint4 qb = vs_sm[(2*c + 1) * 64 + lane];
                float lg = dot8(A0, A1, qa, 0.0f);
                lg = dot8(A2, A3, qb, lg);
                const float mn = fmaxf(m, lg);
                den = den * __expf(m - mn) + __expf(lg - mn);
                m = mn;
            }
            inv = 1.0f / den;
        }

        // phase 2: recompute u_hat (+logit), weight, accumulate into LDS
        #pragma unroll 1
        for (int c = 0; c < NCLS; ++c) {
            float4 A0 = {0,0,0,0}, A1 = {0,0,0,0}, A2 = {0,0,0,0}, A3 = {0,0,0,0};
            #pragma unroll
            for (int i = 0; i < 8; ++i) {
                const float ui = uu[i];
                A0 = fma4(ui, wp[c*32 + i*4 + 0], A0);
                A1 = fma4(ui, wp[c*32 + i*4 + 1], A1);
                A2 = fma4(ui, wp[c*32 + i*4 + 2], A2);
                A3 = fma4(ui, wp[c*32 + i*4 + 3], A3);
            }
            float cc;
            if (FIRST) {
                cc = 0.1f;                        // softmax of zero logits
            } else {
                const uint4 qa = vs_sm[(2*c)     * 64 + lane];
                const uint4 qb = vs_sm[(2*c + 1) * 64 + lane];
                float lg = dot8(A0, A1, qa, 0.0f);
                lg = dot8(A2, A3, qb, lg);
                cc = __expf(lg - m) * inv;
            }
            float* sp = &s_part[lane][c * 16];    // lane-exclusive row, 2-way banks
            atomicAdd(sp + 0,  cc * A0.x);  atomicAdd(sp + 1,  cc * A0.y);
            atomicAdd(sp + 2,  cc * A0.z);  atomicAdd(sp + 3,  cc * A0.w);
            atomicAdd(sp + 4,  cc * A1.x);  atomicAdd(sp + 5,  cc * A1.y);
            atomicAdd(sp + 6,  cc * A1.z);  atomicAdd(sp + 7,  cc * A1.w);
            atomicAdd(sp + 8,  cc * A2.x);  atomicAdd(sp + 9,  cc * A2.y);
            atomicAdd(sp + 10, cc * A2.z);  atomicAdd(sp + 11, cc * A2.w);
            atomicAdd(sp + 12, cc * A3.x);  atomicAdd(sp + 13, cc * A3.y);
            atomicAdd(sp + 14, cc * A3.z);  atomicAdd(sp + 15, cc * A3.w);
        }
    }

    __syncthreads();

    // coalesced store of this block's partial: Pg[(y*npx + x)][bl][m]
    float* pg = Pg + (size_t)((int)blockIdx.y * gridDim.x + (int)blockIdx.x) * (64 * CO);
    for (int idx = tid; idx < 64 * CO; idx += 1024) {
        const int bl = idx / CO;
        const int mm = idx - bl * CO;
        pg[idx] = s_part[bl][mm];
    }
}

// Sum npx x-partials per (b,c,o), then squash. mode: 0 = Vsum = v,
// 1 = Vsum += v, 2 = write final output.
__global__ __launch_bounds__(256)
void caps_reduce_squash(const float* __restrict__ Pg, float* __restrict__ Vsum,
                        float* __restrict__ out, const int mode, const int npx)
{
    const int g = (int)blockIdx.x * 256 + threadIdx.x;   // [0, 81920)
    const int b = g / CO;
    const int m = g - b * CO;
    const int y = b >> 6, bl = b & 63;

    const float* p = Pg + ((size_t)y * npx * 64 + bl) * CO + m;
    float s = 0.0f;
    for (int x = 0; x < npx; ++x)
        s += p[(size_t)x * (64 * CO)];

    // 16 lanes of one (b,c) are contiguous and 16-aligned within the wave
    float ss = s * s;
    ss += __shfl_xor(ss, 1);
    ss += __shfl_xor(ss, 2);
    ss += __shfl_xor(ss, 4);
    ss += __shfl_xor(ss, 8);
    const float f = sqrtf(ss) / (1.0f + ss);   // |s|/(1+|s|^2)
    const float v = f * s;

    if (mode == 2)      out[g] = v;
    else if (mode == 0) Vsum[g] = v;
    else                Vsum[g] += v;
}

extern "C" void kernel_launch(void* const* d_in, const int* in_sizes, int n_in,
                              void* d_out, int out_size, void* d_ws, size_t ws_size,
                              hipStream_t stream)
{
    (void)in_sizes; (void)n_in; (void)out_size;
    const float* U = (const float*)d_in[0];         // [512][1152][8] f32
    const float* W = (const float*)d_in[1];         // [1][1152][10][8][16] f32
    float* out  = (float*)d_out;                    // [512][10][16] f32
    dim3 blk(1024);
    dim3 rgrid((NBATCH * CO) / 256);                // 320 blocks

    const size_t need72 = ((size_t)8 * 72 * 64 * CO + (size_t)NBATCH * CO) * sizeof(float);
    if (ws_size >= need72) {
        const int npx = 72;                         // RCH=16: one r per wave
        float* Pg   = (float*)d_ws;                 // [8][72][64][160] f32 = 23.6 MB
        float* Vsum = Pg + (size_t)8 * npx * 64 * CO;
        dim3 grid(npx, NBATCH / 64);
        caps_pass<16, true ><<<grid, blk, 0, stream>>>(U, W, nullptr, Pg);
        caps_reduce_squash<<<rgrid, 256, 0, stream>>>(Pg, Vsum, nullptr, 0, npx);
        caps_pass<16, false><<<grid, blk, 0, stream>>>(U, W, Vsum, Pg);
        caps_reduce_squash<<<rgrid, 256, 0, stream>>>(Pg, Vsum, nullptr, 1, npx);
        caps_pass<16, false><<<grid, blk, 0, stream>>>(U, W, Vsum, Pg);
        caps_reduce_squash<<<rgrid, 256, 0, stream>>>(Pg, Vsum, out, 2, npx);
    } else {
        const int npx = 64;                         // fallback: proven 21.3 MB budget
        float* Pg   = (float*)d_ws;                 // [8][64][64][160] f32 = 21 MB
        float* Vsum = Pg + (size_t)8 * npx * 64 * CO;
        dim3 grid(npx, NBATCH / 64);
        caps_pass<18, true ><<<grid, blk, 0, stream>>>(U, W, nullptr, Pg);
        caps_reduce_squash<<<rgrid, 256, 0, stream>>>(Pg, Vsum, nullptr, 0, npx);
        caps_pass<18, false><<<grid, blk, 0, stream>>>(U, W, Vsum, Pg);
        caps_reduce_squash<<<rgrid, 256, 0, stream>>>(Pg, Vsum, nullptr, 1, npx);
        caps_pass<18, false><<<grid, blk, 0, stream>>>(U, W, Vsum, Pg);
        caps_reduce_squash<<<rgrid, 256, 0, stream>>>(Pg, Vsum, out, 2, npx);
    }
}